// Round 11
// baseline (386.815 us; speedup 1.0000x reference)
//
#include <hip/hip_runtime.h>
#include <hip/hip_bf16.h>
#include <cstdint>
#include <cstddef>

typedef __bf16 bf16_t;
typedef __attribute__((ext_vector_type(4))) __bf16 bf16x4;
typedef __attribute__((ext_vector_type(8))) __bf16 bf16x8;
typedef __attribute__((ext_vector_type(4))) float f32x4;

#define MFMA16(a, b, c) __builtin_amdgcn_mfma_f32_16x16x32_bf16(a, b, c, 0, 0, 0)

constexpr int LSEQ = 2048;
constexpr int DMODEL = 512;
constexpr int NHEAD = 8;
constexpr int DKH = 64;
constexpr float INV_TEMPER = 0.04419417382415922f;  // 1/sqrt(512)

// ------------------------------------------- transpose+cast W [K][N] f32 -> Wt [N][K] bf16
__global__ __launch_bounds__(256) void k_transpose_cast(const float* __restrict__ in,
                                                        bf16_t* __restrict__ out,
                                                        int K, int N) {
    __shared__ float tile[32][33];
    int n0 = blockIdx.x * 32, k0 = blockIdx.y * 32;
    int tx = threadIdx.x, ty = threadIdx.y;
#pragma unroll
    for (int i = 0; i < 4; i++)
        tile[ty + i * 8][tx] = in[(size_t)(k0 + ty + i * 8) * N + n0 + tx];
    __syncthreads();
#pragma unroll
    for (int i = 0; i < 4; i++)
        out[(size_t)(n0 + ty + i * 8) * K + k0 + tx] = (bf16_t)tile[tx][ty + i * 8];
}

// ------------------------------------------- NT GEMM: C[m][n] = A[m][:]·Bt[n][:] + bias
// MODE 0: A f32 (cast in staging); Q -> Qh (scaled), K -> Kh, V -> Vtp (transposed +
//         within-32 k-slot permutation: location 32c+8hq+e holds V[32c+perm(hq,e)]).
// MODE 1: A bf16; f32 out (final projection).
template <int MODE>
__global__ __launch_bounds__(256) void k_gemm_nt(const void* __restrict__ Av,
                                                 const bf16_t* __restrict__ Bt,
                                                 const float* __restrict__ bias,
                                                 bf16_t* __restrict__ outQ,
                                                 bf16_t* __restrict__ outK,
                                                 bf16_t* __restrict__ outV,
                                                 float* __restrict__ outO, int K) {
    __shared__ bf16_t As[128 * 32];
    __shared__ bf16_t Bs[128 * 32];
    int t = threadIdx.x;
    int lane = t & 63, w = t >> 6;
    int wm = w >> 1, wn = w & 1;
    int rr = lane & 15, hq = lane >> 4;
    int m0 = blockIdx.x * 128, n0 = blockIdx.y * 128;
    int srow = t >> 2, sseg = t & 3;
    const float* gaF = (const float*)Av + (size_t)(m0 + srow) * K + sseg * 8;
    const bf16_t* gaB = (const bf16_t*)Av + (size_t)(m0 + srow) * K + sseg * 8;
    const bf16_t* gb = Bt + (size_t)(n0 + srow) * K + sseg * 8;
    f32x4 acc[4][4] = {};
    for (int k0 = 0; k0 < K; k0 += 32) {
        bf16x8 a0, a1;
        if (MODE == 0) {
            float4 l0 = *reinterpret_cast<const float4*>(gaF + k0);
            float4 h0 = *reinterpret_cast<const float4*>(gaF + k0 + 4);
            float4 l1 = *reinterpret_cast<const float4*>(gaF + (size_t)64 * K + k0);
            float4 h1 = *reinterpret_cast<const float4*>(gaF + (size_t)64 * K + k0 + 4);
            a0[0] = (bf16_t)l0.x; a0[1] = (bf16_t)l0.y; a0[2] = (bf16_t)l0.z; a0[3] = (bf16_t)l0.w;
            a0[4] = (bf16_t)h0.x; a0[5] = (bf16_t)h0.y; a0[6] = (bf16_t)h0.z; a0[7] = (bf16_t)h0.w;
            a1[0] = (bf16_t)l1.x; a1[1] = (bf16_t)l1.y; a1[2] = (bf16_t)l1.z; a1[3] = (bf16_t)l1.w;
            a1[4] = (bf16_t)h1.x; a1[5] = (bf16_t)h1.y; a1[6] = (bf16_t)h1.z; a1[7] = (bf16_t)h1.w;
        } else {
            a0 = *reinterpret_cast<const bf16x8*>(gaB + k0);
            a1 = *reinterpret_cast<const bf16x8*>(gaB + (size_t)64 * K + k0);
        }
        uint4 b0 = *reinterpret_cast<const uint4*>(gb + k0);
        uint4 b1 = *reinterpret_cast<const uint4*>(gb + (size_t)64 * K + k0);
        __syncthreads();
        *reinterpret_cast<bf16x8*>(&As[srow * 32 + sseg * 8]) = a0;
        *reinterpret_cast<bf16x8*>(&As[(srow + 64) * 32 + sseg * 8]) = a1;
        *reinterpret_cast<uint4*>(&Bs[srow * 32 + sseg * 8]) = b0;
        *reinterpret_cast<uint4*>(&Bs[(srow + 64) * 32 + sseg * 8]) = b1;
        __syncthreads();
        bf16x8 af[4], bff[4];
#pragma unroll
        for (int i = 0; i < 4; i++) {
            af[i] = *reinterpret_cast<const bf16x8*>(&As[(wm * 64 + i * 16 + rr) * 32 + hq * 8]);
            bff[i] = *reinterpret_cast<const bf16x8*>(&Bs[(wn * 64 + i * 16 + rr) * 32 + hq * 8]);
        }
#pragma unroll
        for (int mi = 0; mi < 4; mi++)
#pragma unroll
            for (int ni = 0; ni < 4; ni++)
                acc[mi][ni] = MFMA16(af[mi], bff[ni], acc[mi][ni]);
    }
    // epilogue (C/D layout: col = lane&15, row = 4*(lane>>4)+reg  [verified in-harness r6/r7/r10])
#pragma unroll
    for (int mi = 0; mi < 4; mi++) {
#pragma unroll
        for (int ni = 0; ni < 4; ni++) {
            int gn = n0 + wn * 64 + ni * 16 + rr;
            float bv = bias[gn];
            int gmb = m0 + wm * 64 + mi * 16 + hq * 4;
            if (MODE == 0) {
                int which = gn >> 9;        // 0=q 1=k 2=v
                int hn = (gn >> 6) & 7;     // head
                int dk = gn & 63;
                if (which == 2) {
                    // V -> Vtp[bh][dk][pos]; within each 32-token group, location
                    // 8hq+e holds token perm(hq,e) = (e<4 ? 4hq+e : 16+4hq+e-4)  [r10-verified]
#pragma unroll
                    for (int rg = 0; rg < 4; rg++) {
                        int gm = gmb + rg;
                        int bb = gm >> 11, ll = gm & 2047;
                        int pos = (ll & ~31) | ((ll & 0xC) << 1) | ((ll & 0x10) >> 2) | (ll & 3);
                        outV[(((size_t)bb * NHEAD + hn) * DKH + dk) * LSEQ + pos] =
                            (bf16_t)(acc[mi][ni][rg] + bv);
                    }
                } else {
                    bf16_t* dst = which == 0 ? outQ : outK;
                    float scale = which == 0 ? INV_TEMPER : 1.0f;
#pragma unroll
                    for (int rg = 0; rg < 4; rg++) {
                        int gm = gmb + rg;
                        int bb = gm >> 11, ll = gm & 2047;
                        float v = (acc[mi][ni][rg] + bv) * scale;
                        dst[(((size_t)bb * NHEAD + hn) * LSEQ + ll) * DKH + dk] = (bf16_t)v;
                    }
                }
            } else {
#pragma unroll
                for (int rg = 0; rg < 4; rg++) {
                    int gm = gmb + rg;
                    outO[(size_t)gm * DMODEL + gn] = acc[mi][ni][rg] + bv;
                }
            }
        }
    }
}

// ------------------------------------------- fused attention v5: P-in-registers, single K pass
// Identical math/addressing to r10-verified k_attn4, EXCEPT pass B reads P from
// registers (pReg, bf16, statically indexed) instead of recomputing QK^T.
// K and mask are read ONCE; 64 MFMAs + 128 exps per lane removed vs r10.
__global__ __launch_bounds__(256, 4) void k_attn5(const bf16_t* __restrict__ Qh,
                                                  const bf16_t* __restrict__ Kh,
                                                  const bf16_t* __restrict__ Vtp,
                                                  const int* __restrict__ mask,
                                                  float* __restrict__ attn_out,
                                                  bf16_t* __restrict__ Obf) {
    __shared__ float sO[4 * 16 * 65];   // per-wave O partials, padded stride 65
    __shared__ float rpart[16 * 17];    // [row rr][w*4+hq], padded stride 17
    int t = threadIdx.x;
    int lane = t & 63, w = t >> 6;
    int rr = lane & 15, hq = lane >> 4;
    int bid = blockIdx.x;
    int h = bid & 7, b = (bid >> 3) & 1, qt = bid >> 4;
    int q0 = qt * 16;
    int bh = b * NHEAD + h;

    // Q fragments (rows q0..q0+15, d-slots hq*8..+7; two 32-k steps)
    const bf16_t* qp = Qh + ((size_t)bh * LSEQ + q0 + rr) * DKH + hq * 8;
    bf16x8 qf0 = *reinterpret_cast<const bf16x8*>(qp);
    bf16x8 qf1 = *reinterpret_cast<const bf16x8*>(qp + 32);

    const bf16_t* kb = Kh + (size_t)bh * LSEQ * DKH;
    const int* mrow = mask + ((size_t)b * LSEQ + q0 + rr) * LSEQ;

    // ---- pass A: QK^T + mask + exp -> pReg (bf16) + row sums. Wave w: cols [w*512,+512)
    bf16x4 pReg[32];                    // 64 VGPRs; ALL indices compile-time (rule #20)
    float rs = 0.f;
#pragma unroll
    for (int nt = 0; nt < 32; nt++) {
        int cb = w * 512 + nt * 16;
        const bf16_t* kp = kb + (size_t)(cb + rr) * DKH + hq * 8;
        bf16x8 kf0 = *reinterpret_cast<const bf16x8*>(kp);
        bf16x8 kf1 = *reinterpret_cast<const bf16x8*>(kp + 32);
        f32x4 acc = {0.f, 0.f, 0.f, 0.f};
        acc = MFMA16(kf0, qf0, acc);   // swapped: D[i] = S[q0+rr][cb+4*hq+i]  [r10-verified]
        acc = MFMA16(kf1, qf1, acc);
        int4 mv = *reinterpret_cast<const int4*>(mrow + cb + hq * 4);
        // no max-subtraction: scores O(1); masked -> 0 exactly as reference
        float e0 = mv.x ? 0.f : __expf(acc[0]);
        float e1 = mv.y ? 0.f : __expf(acc[1]);
        float e2 = mv.z ? 0.f : __expf(acc[2]);
        float e3 = mv.w ? 0.f : __expf(acc[3]);
        rs += (e0 + e1) + (e2 + e3);
        bf16x4 pb;
        pb[0] = (bf16_t)e0; pb[1] = (bf16_t)e1; pb[2] = (bf16_t)e2; pb[3] = (bf16_t)e3;
        pReg[nt] = pb;
    }
    // shuffle-free rowsum reduce: 16 partials per row (4 waves x 4 hq groups)  [r10-verified]
    rpart[rr * 17 + w * 4 + hq] = rs;
    __syncthreads();
    float sum = 0.f;
#pragma unroll
    for (int j = 0; j < 16; j++) sum += rpart[rr * 17 + j];
    float invr = 1.0f / sum;

    // ---- pass B: normalize from registers -> attns write + swapped PV  [r10 addressing]
    const bf16_t* vb = Vtp + (size_t)bh * DKH * LSEQ;
    float* arow = attn_out + ((size_t)(h * 2 + b) * LSEQ + q0 + rr) * LSEQ;
    f32x4 osum[4] = {};
#pragma unroll
    for (int j = 0; j < 16; j++) {
        int cb0 = w * 512 + j * 32;
        bf16x4 b0 = pReg[2 * j];
        bf16x4 b1 = pReg[2 * j + 1];
        float p0 = (float)b0[0] * invr, p1 = (float)b0[1] * invr;
        float p2 = (float)b0[2] * invr, p3 = (float)b0[3] * invr;
        float p4 = (float)b1[0] * invr, p5 = (float)b1[1] * invr;
        float p6 = (float)b1[2] * invr, p7 = (float)b1[3] * invr;
        // attns: lane (rr,hq) holds row q0+rr, cols cb0+4hq+i and cb0+16+4hq+i
        float4 w0 = {p0, p1, p2, p3}, w1 = {p4, p5, p6, p7};
        *reinterpret_cast<float4*>(arow + cb0 + hq * 4) = w0;
        *reinterpret_cast<float4*>(arow + cb0 + 16 + hq * 4) = w1;
        // PV swapped: A = Vtp (slot e holds V[cb0+perm(hq,e)][d]),
        //             B = P regs (slot e holds P[q0+rr][cb0+perm(hq,e)]) -> same k ✓
        bf16x8 pa;
        pa[0] = (bf16_t)p0; pa[1] = (bf16_t)p1; pa[2] = (bf16_t)p2; pa[3] = (bf16_t)p3;
        pa[4] = (bf16_t)p4; pa[5] = (bf16_t)p5; pa[6] = (bf16_t)p6; pa[7] = (bf16_t)p7;
#pragma unroll
        for (int ntile = 0; ntile < 4; ntile++) {
            bf16x8 vf = *reinterpret_cast<const bf16x8*>(
                vb + (size_t)(ntile * 16 + rr) * LSEQ + cb0 + hq * 8);
            osum[ntile] = MFMA16(vf, pa, osum[ntile]);  // D: O[q0+rr][16nt+4hq+i]
        }
    }
    // cross-wave O reduce: lane (rr,hq) holds O[q0+rr][d = 16*ntile + 4hq + i]  [r10-verified]
#pragma unroll
    for (int ntile = 0; ntile < 4; ntile++)
#pragma unroll
        for (int i = 0; i < 4; i++)
            sO[w * 1040 + rr * 65 + ntile * 16 + hq * 4 + i] = osum[ntile][i];
    __syncthreads();
#pragma unroll
    for (int i = 0; i < 4; i++) {
        int e = i * 256 + t;
        int orow = e >> 6, oc = e & 63;
        float v = sO[orow * 65 + oc] + sO[1040 + orow * 65 + oc] +
                  sO[2080 + orow * 65 + oc] + sO[3120 + orow * 65 + oc];
        Obf[(((size_t)b * LSEQ + q0 + orow) * NHEAD + h) * DKH + oc] = (bf16_t)v;
    }
}

// ----------------------------------------------------------------------- launch
extern "C" void kernel_launch(void* const* d_in, const int* in_sizes, int n_in,
                              void* d_out, int out_size, void* d_ws, size_t ws_size,
                              hipStream_t stream) {
    (void)in_sizes; (void)n_in; (void)out_size; (void)ws_size;
    const float* q = (const float*)d_in[0];
    const int* mask = (const int*)d_in[3];   // int32 (verified r6)
    const float* W_qkv = (const float*)d_in[4];
    const float* b_qkv = (const float*)d_in[5];
    const float* W_proj = (const float*)d_in[6];
    const float* b_proj = (const float*)d_in[7];
    float* out = (float*)d_out;
    float* attn_out = out + (size_t)2 * LSEQ * DMODEL;  // f32 elements

    char* ws = (char*)d_ws;
    bf16_t* wqkv_t = (bf16_t*)(ws);                   // 1.5 MB
    bf16_t* wproj_t = (bf16_t*)(ws + 1572864);        // 0.5 MB
    bf16_t* Qh = (bf16_t*)(ws + 2097152);             // 4 MB
    bf16_t* Kh = (bf16_t*)(ws + 6291456);             // 4 MB
    bf16_t* Vtp = (bf16_t*)(ws + 10485760);           // 4 MB
    bf16_t* Obf = (bf16_t*)(ws + 14680064);           // 4 MB  (total 18 MB)

    k_transpose_cast<<<dim3(48, 16), dim3(32, 8), 0, stream>>>(W_qkv, wqkv_t, 512, 1536);
    k_transpose_cast<<<dim3(16, 16), dim3(32, 8), 0, stream>>>(W_proj, wproj_t, 512, 512);
    k_gemm_nt<0><<<dim3(32, 12), 256, 0, stream>>>(q, wqkv_t, b_qkv, Qh, Kh, Vtp, nullptr, 512);
    k_attn5<<<2048, 256, 0, stream>>>(Qh, Kh, Vtp, mask, attn_out, Obf);
    k_gemm_nt<1><<<dim3(32, 4), 256, 0, stream>>>(Obf, wproj_t, b_proj, nullptr, nullptr, nullptr, out, 512);
}

// Round 12
// 261.832 us; speedup vs baseline: 1.4773x; 1.4773x over previous
//
#include <hip/hip_runtime.h>
#include <hip/hip_bf16.h>
#include <cstdint>
#include <cstddef>

typedef __bf16 bf16_t;
typedef __attribute__((ext_vector_type(4))) __bf16 bf16x4;
typedef __attribute__((ext_vector_type(8))) __bf16 bf16x8;
typedef __attribute__((ext_vector_type(4))) float f32x4;

#define MFMA16(a, b, c) __builtin_amdgcn_mfma_f32_16x16x32_bf16(a, b, c, 0, 0, 0)

constexpr int LSEQ = 2048;
constexpr int DMODEL = 512;
constexpr int NHEAD = 8;
constexpr int DKH = 64;
constexpr float INV_TEMPER = 0.04419417382415922f;  // 1/sqrt(512)

// ------------------------------------------- transpose+cast W [K][N] f32 -> Wt [N][K] bf16
__global__ __launch_bounds__(256) void k_transpose_cast(const float* __restrict__ in,
                                                        bf16_t* __restrict__ out,
                                                        int K, int N) {
    __shared__ float tile[32][33];
    int n0 = blockIdx.x * 32, k0 = blockIdx.y * 32;
    int tx = threadIdx.x, ty = threadIdx.y;
#pragma unroll
    for (int i = 0; i < 4; i++)
        tile[ty + i * 8][tx] = in[(size_t)(k0 + ty + i * 8) * N + n0 + tx];
    __syncthreads();
#pragma unroll
    for (int i = 0; i < 4; i++)
        out[(size_t)(n0 + ty + i * 8) * K + k0 + tx] = (bf16_t)tile[tx][ty + i * 8];
}

// ------------------------------------------- NT GEMM: C[m][n] = A[m][:]·Bt[n][:] + bias
// MODE 0: A f32 (cast in staging); Q -> Qh (scaled), K -> Kh, V -> Vtp (transposed +
//         within-32 k-slot permutation: location 32c+8hq+e holds V[32c+perm(hq,e)]).
// MODE 1: A bf16; f32 out (final projection).
template <int MODE>
__global__ __launch_bounds__(256) void k_gemm_nt(const void* __restrict__ Av,
                                                 const bf16_t* __restrict__ Bt,
                                                 const float* __restrict__ bias,
                                                 bf16_t* __restrict__ outQ,
                                                 bf16_t* __restrict__ outK,
                                                 bf16_t* __restrict__ outV,
                                                 float* __restrict__ outO, int K) {
    __shared__ bf16_t As[128 * 32];
    __shared__ bf16_t Bs[128 * 32];
    int t = threadIdx.x;
    int lane = t & 63, w = t >> 6;
    int wm = w >> 1, wn = w & 1;
    int rr = lane & 15, hq = lane >> 4;
    int m0 = blockIdx.x * 128, n0 = blockIdx.y * 128;
    int srow = t >> 2, sseg = t & 3;
    const float* gaF = (const float*)Av + (size_t)(m0 + srow) * K + sseg * 8;
    const bf16_t* gaB = (const bf16_t*)Av + (size_t)(m0 + srow) * K + sseg * 8;
    const bf16_t* gb = Bt + (size_t)(n0 + srow) * K + sseg * 8;
    f32x4 acc[4][4] = {};
    for (int k0 = 0; k0 < K; k0 += 32) {
        bf16x8 a0, a1;
        if (MODE == 0) {
            float4 l0 = *reinterpret_cast<const float4*>(gaF + k0);
            float4 h0 = *reinterpret_cast<const float4*>(gaF + k0 + 4);
            float4 l1 = *reinterpret_cast<const float4*>(gaF + (size_t)64 * K + k0);
            float4 h1 = *reinterpret_cast<const float4*>(gaF + (size_t)64 * K + k0 + 4);
            a0[0] = (bf16_t)l0.x; a0[1] = (bf16_t)l0.y; a0[2] = (bf16_t)l0.z; a0[3] = (bf16_t)l0.w;
            a0[4] = (bf16_t)h0.x; a0[5] = (bf16_t)h0.y; a0[6] = (bf16_t)h0.z; a0[7] = (bf16_t)h0.w;
            a1[0] = (bf16_t)l1.x; a1[1] = (bf16_t)l1.y; a1[2] = (bf16_t)l1.z; a1[3] = (bf16_t)l1.w;
            a1[4] = (bf16_t)h1.x; a1[5] = (bf16_t)h1.y; a1[6] = (bf16_t)h1.z; a1[7] = (bf16_t)h1.w;
        } else {
            a0 = *reinterpret_cast<const bf16x8*>(gaB + k0);
            a1 = *reinterpret_cast<const bf16x8*>(gaB + (size_t)64 * K + k0);
        }
        uint4 b0 = *reinterpret_cast<const uint4*>(gb + k0);
        uint4 b1 = *reinterpret_cast<const uint4*>(gb + (size_t)64 * K + k0);
        __syncthreads();
        *reinterpret_cast<bf16x8*>(&As[srow * 32 + sseg * 8]) = a0;
        *reinterpret_cast<bf16x8*>(&As[(srow + 64) * 32 + sseg * 8]) = a1;
        *reinterpret_cast<uint4*>(&Bs[srow * 32 + sseg * 8]) = b0;
        *reinterpret_cast<uint4*>(&Bs[(srow + 64) * 32 + sseg * 8]) = b1;
        __syncthreads();
        bf16x8 af[4], bff[4];
#pragma unroll
        for (int i = 0; i < 4; i++) {
            af[i] = *reinterpret_cast<const bf16x8*>(&As[(wm * 64 + i * 16 + rr) * 32 + hq * 8]);
            bff[i] = *reinterpret_cast<const bf16x8*>(&Bs[(wn * 64 + i * 16 + rr) * 32 + hq * 8]);
        }
#pragma unroll
        for (int mi = 0; mi < 4; mi++)
#pragma unroll
            for (int ni = 0; ni < 4; ni++)
                acc[mi][ni] = MFMA16(af[mi], bff[ni], acc[mi][ni]);
    }
    // epilogue (C/D layout: col = lane&15, row = 4*(lane>>4)+reg  [verified in-harness r6/r7/r10])
#pragma unroll
    for (int mi = 0; mi < 4; mi++) {
#pragma unroll
        for (int ni = 0; ni < 4; ni++) {
            int gn = n0 + wn * 64 + ni * 16 + rr;
            float bv = bias[gn];
            int gmb = m0 + wm * 64 + mi * 16 + hq * 4;
            if (MODE == 0) {
                int which = gn >> 9;        // 0=q 1=k 2=v
                int hn = (gn >> 6) & 7;     // head
                int dk = gn & 63;
                if (which == 2) {
                    // V -> Vtp[bh][dk][pos]; within each 32-token group, location
                    // 8hq+e holds token perm(hq,e) = (e<4 ? 4hq+e : 16+4hq+e-4)  [r10-verified]
#pragma unroll
                    for (int rg = 0; rg < 4; rg++) {
                        int gm = gmb + rg;
                        int bb = gm >> 11, ll = gm & 2047;
                        int pos = (ll & ~31) | ((ll & 0xC) << 1) | ((ll & 0x10) >> 2) | (ll & 3);
                        outV[(((size_t)bb * NHEAD + hn) * DKH + dk) * LSEQ + pos] =
                            (bf16_t)(acc[mi][ni][rg] + bv);
                    }
                } else {
                    bf16_t* dst = which == 0 ? outQ : outK;
                    float scale = which == 0 ? INV_TEMPER : 1.0f;
#pragma unroll
                    for (int rg = 0; rg < 4; rg++) {
                        int gm = gmb + rg;
                        int bb = gm >> 11, ll = gm & 2047;
                        float v = (acc[mi][ni][rg] + bv) * scale;
                        dst[(((size_t)bb * NHEAD + hn) * LSEQ + ll) * DKH + dk] = (bf16_t)v;
                    }
                }
            } else {
#pragma unroll
                for (int rg = 0; rg < 4; rg++) {
                    int gm = gmb + rg;
                    outO[(size_t)gm * DMODEL + gn] = acc[mi][ni][rg] + bv;
                }
            }
        }
    }
}

// ------------------------------------------- fused attention v6: P-in-registers, no spill
// r11's k_attn5 with (a) launch_bounds(256,3) so pReg stays in VGPRs (r11 spilled at
// the (256,4) 128-VGPR cap -> 420 MB scratch traffic), (b) PV uses UNNORMALIZED bf16 P
// directly from pReg (zero repack) with 1/sum folded into the O epilogue (r7-class numerics).
__global__ __launch_bounds__(256, 3) void k_attn6(const bf16_t* __restrict__ Qh,
                                                  const bf16_t* __restrict__ Kh,
                                                  const bf16_t* __restrict__ Vtp,
                                                  const int* __restrict__ mask,
                                                  float* __restrict__ attn_out,
                                                  bf16_t* __restrict__ Obf) {
    __shared__ float sO[4 * 16 * 65];   // per-wave O partials, padded stride 65
    __shared__ float rpart[16 * 17];    // [row rr][w*4+hq], padded stride 17
    int t = threadIdx.x;
    int lane = t & 63, w = t >> 6;
    int rr = lane & 15, hq = lane >> 4;
    int bid = blockIdx.x;
    int h = bid & 7, b = (bid >> 3) & 1, qt = bid >> 4;
    int q0 = qt * 16;
    int bh = b * NHEAD + h;

    // Q fragments (rows q0..q0+15, d-slots hq*8..+7; two 32-k steps)
    const bf16_t* qp = Qh + ((size_t)bh * LSEQ + q0 + rr) * DKH + hq * 8;
    bf16x8 qf0 = *reinterpret_cast<const bf16x8*>(qp);
    bf16x8 qf1 = *reinterpret_cast<const bf16x8*>(qp + 32);

    const bf16_t* kb = Kh + (size_t)bh * LSEQ * DKH;
    const int* mrow = mask + ((size_t)b * LSEQ + q0 + rr) * LSEQ;

    // ---- pass A: QK^T + mask + exp -> pReg (bf16, unnormalized) + row sums
    bf16x4 pReg[32];                    // 64 VGPRs; ALL indices compile-time (rule #20)
    float rs = 0.f;
#pragma unroll
    for (int nt = 0; nt < 32; nt++) {
        int cb = w * 512 + nt * 16;
        const bf16_t* kp = kb + (size_t)(cb + rr) * DKH + hq * 8;
        bf16x8 kf0 = *reinterpret_cast<const bf16x8*>(kp);
        bf16x8 kf1 = *reinterpret_cast<const bf16x8*>(kp + 32);
        f32x4 acc = {0.f, 0.f, 0.f, 0.f};
        acc = MFMA16(kf0, qf0, acc);   // swapped: D[i] = S[q0+rr][cb+4*hq+i]  [r10-verified]
        acc = MFMA16(kf1, qf1, acc);
        int4 mv = *reinterpret_cast<const int4*>(mrow + cb + hq * 4);
        // no max-subtraction: scores O(1); masked -> 0 exactly as reference
        float e0 = mv.x ? 0.f : __expf(acc[0]);
        float e1 = mv.y ? 0.f : __expf(acc[1]);
        float e2 = mv.z ? 0.f : __expf(acc[2]);
        float e3 = mv.w ? 0.f : __expf(acc[3]);
        rs += (e0 + e1) + (e2 + e3);
        bf16x4 pb;
        pb[0] = (bf16_t)e0; pb[1] = (bf16_t)e1; pb[2] = (bf16_t)e2; pb[3] = (bf16_t)e3;
        pReg[nt] = pb;
    }
    // shuffle-free rowsum reduce: 16 partials per row (4 waves x 4 hq groups)  [r10-verified]
    rpart[rr * 17 + w * 4 + hq] = rs;
    __syncthreads();
    float sum = 0.f;
#pragma unroll
    for (int j = 0; j < 16; j++) sum += rpart[rr * 17 + j];
    float invr = 1.0f / sum;

    // ---- pass B: attns write (normalized f32) + swapped PV on unnormalized P
    const bf16_t* vb = Vtp + (size_t)bh * DKH * LSEQ;
    float* arow = attn_out + ((size_t)(h * 2 + b) * LSEQ + q0 + rr) * LSEQ;
    f32x4 osum[4] = {};
#pragma unroll
    for (int j = 0; j < 16; j++) {
        int cb0 = w * 512 + j * 32;
        bf16x4 b0 = pReg[2 * j];
        bf16x4 b1 = pReg[2 * j + 1];
        // attns: lane (rr,hq) holds row q0+rr, cols cb0+4hq+i and cb0+16+4hq+i
        float4 w0 = {(float)b0[0] * invr, (float)b0[1] * invr,
                     (float)b0[2] * invr, (float)b0[3] * invr};
        float4 w1 = {(float)b1[0] * invr, (float)b1[1] * invr,
                     (float)b1[2] * invr, (float)b1[3] * invr};
        *reinterpret_cast<float4*>(arow + cb0 + hq * 4) = w0;
        *reinterpret_cast<float4*>(arow + cb0 + 16 + hq * 4) = w1;
        // PV swapped [r10-verified]: A = Vtp (slot e: V[cb0+perm(hq,e)][d]),
        // B = pReg as-is (slot e: P_unnorm[q0+rr][cb0+perm(hq,e)]) -> same k ✓
        bf16x8 pa;
        pa[0] = b0[0]; pa[1] = b0[1]; pa[2] = b0[2]; pa[3] = b0[3];
        pa[4] = b1[0]; pa[5] = b1[1]; pa[6] = b1[2]; pa[7] = b1[3];
#pragma unroll
        for (int ntile = 0; ntile < 4; ntile++) {
            bf16x8 vf = *reinterpret_cast<const bf16x8*>(
                vb + (size_t)(ntile * 16 + rr) * LSEQ + cb0 + hq * 8);
            osum[ntile] = MFMA16(vf, pa, osum[ntile]);  // D: O_unnorm[q0+rr][16nt+4hq+i]
        }
    }
    // cross-wave O reduce; invr (row q0+rr's inverse, lane-local) folded here  [r10 pattern]
#pragma unroll
    for (int ntile = 0; ntile < 4; ntile++)
#pragma unroll
        for (int i = 0; i < 4; i++)
            sO[w * 1040 + rr * 65 + ntile * 16 + hq * 4 + i] = osum[ntile][i] * invr;
    __syncthreads();
#pragma unroll
    for (int i = 0; i < 4; i++) {
        int e = i * 256 + t;
        int orow = e >> 6, oc = e & 63;
        float v = sO[orow * 65 + oc] + sO[1040 + orow * 65 + oc] +
                  sO[2080 + orow * 65 + oc] + sO[3120 + orow * 65 + oc];
        Obf[(((size_t)b * LSEQ + q0 + orow) * NHEAD + h) * DKH + oc] = (bf16_t)v;
    }
}

// ----------------------------------------------------------------------- launch
extern "C" void kernel_launch(void* const* d_in, const int* in_sizes, int n_in,
                              void* d_out, int out_size, void* d_ws, size_t ws_size,
                              hipStream_t stream) {
    (void)in_sizes; (void)n_in; (void)out_size; (void)ws_size;
    const float* q = (const float*)d_in[0];
    const int* mask = (const int*)d_in[3];   // int32 (verified r6)
    const float* W_qkv = (const float*)d_in[4];
    const float* b_qkv = (const float*)d_in[5];
    const float* W_proj = (const float*)d_in[6];
    const float* b_proj = (const float*)d_in[7];
    float* out = (float*)d_out;
    float* attn_out = out + (size_t)2 * LSEQ * DMODEL;  // f32 elements

    char* ws = (char*)d_ws;
    bf16_t* wqkv_t = (bf16_t*)(ws);                   // 1.5 MB
    bf16_t* wproj_t = (bf16_t*)(ws + 1572864);        // 0.5 MB
    bf16_t* Qh = (bf16_t*)(ws + 2097152);             // 4 MB
    bf16_t* Kh = (bf16_t*)(ws + 6291456);             // 4 MB
    bf16_t* Vtp = (bf16_t*)(ws + 10485760);           // 4 MB
    bf16_t* Obf = (bf16_t*)(ws + 14680064);           // 4 MB  (total 18 MB)

    k_transpose_cast<<<dim3(48, 16), dim3(32, 8), 0, stream>>>(W_qkv, wqkv_t, 512, 1536);
    k_transpose_cast<<<dim3(16, 16), dim3(32, 8), 0, stream>>>(W_proj, wproj_t, 512, 512);
    k_gemm_nt<0><<<dim3(32, 12), 256, 0, stream>>>(q, wqkv_t, b_qkv, Qh, Kh, Vtp, nullptr, 512);
    k_attn6<<<2048, 256, 0, stream>>>(Qh, Kh, Vtp, mask, attn_out, Obf);
    k_gemm_nt<1><<<dim3(32, 4), 256, 0, stream>>>(Obf, wproj_t, b_proj, nullptr, nullptr, nullptr, out, 512);
}

// Round 13
// 246.519 us; speedup vs baseline: 1.5691x; 1.0621x over previous
//
#include <hip/hip_runtime.h>
#include <hip/hip_bf16.h>
#include <cstdint>
#include <cstddef>

typedef __bf16 bf16_t;
typedef __attribute__((ext_vector_type(4))) __bf16 bf16x4;
typedef __attribute__((ext_vector_type(8))) __bf16 bf16x8;
typedef __attribute__((ext_vector_type(4))) float f32x4;

#define MFMA16(a, b, c) __builtin_amdgcn_mfma_f32_16x16x32_bf16(a, b, c, 0, 0, 0)

constexpr int LSEQ = 2048;
constexpr int DMODEL = 512;
constexpr int NHEAD = 8;
constexpr int DKH = 64;
constexpr float INV_TEMPER = 0.04419417382415922f;  // 1/sqrt(512)

// ------------------------------------------- transpose+cast W [K][N] f32 -> Wt [N][K] bf16
__global__ __launch_bounds__(256) void k_transpose_cast(const float* __restrict__ in,
                                                        bf16_t* __restrict__ out,
                                                        int K, int N) {
    __shared__ float tile[32][33];
    int n0 = blockIdx.x * 32, k0 = blockIdx.y * 32;
    int tx = threadIdx.x, ty = threadIdx.y;
#pragma unroll
    for (int i = 0; i < 4; i++)
        tile[ty + i * 8][tx] = in[(size_t)(k0 + ty + i * 8) * N + n0 + tx];
    __syncthreads();
#pragma unroll
    for (int i = 0; i < 4; i++)
        out[(size_t)(n0 + ty + i * 8) * K + k0 + tx] = (bf16_t)tile[tx][ty + i * 8];
}

// ------------------------------------------- NT GEMM: C[m][n] = A[m][:]·Bt[n][:] + bias
// MODE 0: A f32 (cast in staging); Q -> Qh (scaled), K -> Kh, V -> Vtp (transposed +
//         within-32 k-slot permutation: location 32c+8hq+e holds V[32c+perm(hq,e)]).
// MODE 1: A bf16; f32 out (final projection).
template <int MODE>
__global__ __launch_bounds__(256) void k_gemm_nt(const void* __restrict__ Av,
                                                 const bf16_t* __restrict__ Bt,
                                                 const float* __restrict__ bias,
                                                 bf16_t* __restrict__ outQ,
                                                 bf16_t* __restrict__ outK,
                                                 bf16_t* __restrict__ outV,
                                                 float* __restrict__ outO, int K) {
    __shared__ bf16_t As[128 * 32];
    __shared__ bf16_t Bs[128 * 32];
    int t = threadIdx.x;
    int lane = t & 63, w = t >> 6;
    int wm = w >> 1, wn = w & 1;
    int rr = lane & 15, hq = lane >> 4;
    int m0 = blockIdx.x * 128, n0 = blockIdx.y * 128;
    int srow = t >> 2, sseg = t & 3;
    const float* gaF = (const float*)Av + (size_t)(m0 + srow) * K + sseg * 8;
    const bf16_t* gaB = (const bf16_t*)Av + (size_t)(m0 + srow) * K + sseg * 8;
    const bf16_t* gb = Bt + (size_t)(n0 + srow) * K + sseg * 8;
    f32x4 acc[4][4] = {};
    for (int k0 = 0; k0 < K; k0 += 32) {
        bf16x8 a0, a1;
        if (MODE == 0) {
            float4 l0 = *reinterpret_cast<const float4*>(gaF + k0);
            float4 h0 = *reinterpret_cast<const float4*>(gaF + k0 + 4);
            float4 l1 = *reinterpret_cast<const float4*>(gaF + (size_t)64 * K + k0);
            float4 h1 = *reinterpret_cast<const float4*>(gaF + (size_t)64 * K + k0 + 4);
            a0[0] = (bf16_t)l0.x; a0[1] = (bf16_t)l0.y; a0[2] = (bf16_t)l0.z; a0[3] = (bf16_t)l0.w;
            a0[4] = (bf16_t)h0.x; a0[5] = (bf16_t)h0.y; a0[6] = (bf16_t)h0.z; a0[7] = (bf16_t)h0.w;
            a1[0] = (bf16_t)l1.x; a1[1] = (bf16_t)l1.y; a1[2] = (bf16_t)l1.z; a1[3] = (bf16_t)l1.w;
            a1[4] = (bf16_t)h1.x; a1[5] = (bf16_t)h1.y; a1[6] = (bf16_t)h1.z; a1[7] = (bf16_t)h1.w;
        } else {
            a0 = *reinterpret_cast<const bf16x8*>(gaB + k0);
            a1 = *reinterpret_cast<const bf16x8*>(gaB + (size_t)64 * K + k0);
        }
        uint4 b0 = *reinterpret_cast<const uint4*>(gb + k0);
        uint4 b1 = *reinterpret_cast<const uint4*>(gb + (size_t)64 * K + k0);
        __syncthreads();
        *reinterpret_cast<bf16x8*>(&As[srow * 32 + sseg * 8]) = a0;
        *reinterpret_cast<bf16x8*>(&As[(srow + 64) * 32 + sseg * 8]) = a1;
        *reinterpret_cast<uint4*>(&Bs[srow * 32 + sseg * 8]) = b0;
        *reinterpret_cast<uint4*>(&Bs[(srow + 64) * 32 + sseg * 8]) = b1;
        __syncthreads();
        bf16x8 af[4], bff[4];
#pragma unroll
        for (int i = 0; i < 4; i++) {
            af[i] = *reinterpret_cast<const bf16x8*>(&As[(wm * 64 + i * 16 + rr) * 32 + hq * 8]);
            bff[i] = *reinterpret_cast<const bf16x8*>(&Bs[(wn * 64 + i * 16 + rr) * 32 + hq * 8]);
        }
#pragma unroll
        for (int mi = 0; mi < 4; mi++)
#pragma unroll
            for (int ni = 0; ni < 4; ni++)
                acc[mi][ni] = MFMA16(af[mi], bff[ni], acc[mi][ni]);
    }
    // epilogue (C/D layout: col = lane&15, row = 4*(lane>>4)+reg  [verified in-harness r6/r7/r10])
#pragma unroll
    for (int mi = 0; mi < 4; mi++) {
#pragma unroll
        for (int ni = 0; ni < 4; ni++) {
            int gn = n0 + wn * 64 + ni * 16 + rr;
            float bv = bias[gn];
            int gmb = m0 + wm * 64 + mi * 16 + hq * 4;
            if (MODE == 0) {
                int which = gn >> 9;        // 0=q 1=k 2=v
                int hn = (gn >> 6) & 7;     // head
                int dk = gn & 63;
                if (which == 2) {
                    // V -> Vtp[bh][dk][pos]; within each 32-token group, location
                    // 8hq+e holds token perm(hq,e) = (e<4 ? 4hq+e : 16+4hq+e-4)  [r10-verified]
#pragma unroll
                    for (int rg = 0; rg < 4; rg++) {
                        int gm = gmb + rg;
                        int bb = gm >> 11, ll = gm & 2047;
                        int pos = (ll & ~31) | ((ll & 0xC) << 1) | ((ll & 0x10) >> 2) | (ll & 3);
                        outV[(((size_t)bb * NHEAD + hn) * DKH + dk) * LSEQ + pos] =
                            (bf16_t)(acc[mi][ni][rg] + bv);
                    }
                } else {
                    bf16_t* dst = which == 0 ? outQ : outK;
                    float scale = which == 0 ? INV_TEMPER : 1.0f;
#pragma unroll
                    for (int rg = 0; rg < 4; rg++) {
                        int gm = gmb + rg;
                        int bb = gm >> 11, ll = gm & 2047;
                        float v = (acc[mi][ni][rg] + bv) * scale;
                        dst[(((size_t)bb * NHEAD + hn) * LSEQ + ll) * DKH + dk] = (bf16_t)v;
                    }
                }
            } else {
#pragma unroll
                for (int rg = 0; rg < 4; rg++) {
                    int gm = gmb + rg;
                    outO[(size_t)gm * DMODEL + gn] = acc[mi][ni][rg] + bv;
                }
            }
        }
    }
}

// ------------------------------------------- fused attention v7: NAMED-REGISTER P, no array
// r12's k_attn6 with pReg[32] replaced by 32 named bf16x4 variables and both passes
// macro-expanded to straight-line code (rule #20: arrays with big loop bodies fail
// SROA -> scratch; r12 counters proved it: VGPR=84, +116 MB scratch WRITE).
__global__ __launch_bounds__(256, 3) void k_attn7(const bf16_t* __restrict__ Qh,
                                                  const bf16_t* __restrict__ Kh,
                                                  const bf16_t* __restrict__ Vtp,
                                                  const int* __restrict__ mask,
                                                  float* __restrict__ attn_out,
                                                  bf16_t* __restrict__ Obf) {
    __shared__ float sO[4 * 16 * 65];   // per-wave O partials, padded stride 65
    __shared__ float rpart[16 * 17];    // [row rr][w*4+hq], padded stride 17
    int t = threadIdx.x;
    int lane = t & 63, w = t >> 6;
    int rr = lane & 15, hq = lane >> 4;
    int bid = blockIdx.x;
    int h = bid & 7, b = (bid >> 3) & 1, qt = bid >> 4;
    int q0 = qt * 16;
    int bh = b * NHEAD + h;

    const bf16_t* qp = Qh + ((size_t)bh * LSEQ + q0 + rr) * DKH + hq * 8;
    bf16x8 qf0 = *reinterpret_cast<const bf16x8*>(qp);
    bf16x8 qf1 = *reinterpret_cast<const bf16x8*>(qp + 32);

    const bf16_t* kb = Kh + (size_t)bh * LSEQ * DKH;
    const int* mrow = mask + ((size_t)b * LSEQ + q0 + rr) * LSEQ;

    // 32 named P fragments (bf16x4 = 2 VGPRs each; NO array -> NO SROA needed)
    bf16x4 p0, p1, p2, p3, p4, p5, p6, p7, p8, p9, p10, p11, p12, p13, p14, p15,
           p16, p17, p18, p19, p20, p21, p22, p23, p24, p25, p26, p27, p28, p29, p30, p31;
    float rs = 0.f;

    // ---- pass A: QK^T + mask + exp -> named P (unnormalized) + row sum
    // swapped MFMA [r10-verified]: D[i] = S[q0+rr][cb+4*hq+i]
#define QK_STEP(NT, PD)                                                                  \
    {                                                                                    \
        int cb = w * 512 + (NT) * 16;                                                    \
        const bf16_t* kp = kb + (size_t)(cb + rr) * DKH + hq * 8;                        \
        bf16x8 kf0 = *reinterpret_cast<const bf16x8*>(kp);                               \
        bf16x8 kf1 = *reinterpret_cast<const bf16x8*>(kp + 32);                          \
        f32x4 acc = {0.f, 0.f, 0.f, 0.f};                                                \
        acc = MFMA16(kf0, qf0, acc);                                                     \
        acc = MFMA16(kf1, qf1, acc);                                                     \
        int4 mv = *reinterpret_cast<const int4*>(mrow + cb + hq * 4);                    \
        float e0 = mv.x ? 0.f : __expf(acc[0]);                                          \
        float e1 = mv.y ? 0.f : __expf(acc[1]);                                          \
        float e2 = mv.z ? 0.f : __expf(acc[2]);                                          \
        float e3 = mv.w ? 0.f : __expf(acc[3]);                                          \
        rs += (e0 + e1) + (e2 + e3);                                                     \
        PD[0] = (bf16_t)e0; PD[1] = (bf16_t)e1; PD[2] = (bf16_t)e2; PD[3] = (bf16_t)e3;  \
    }
    QK_STEP(0, p0)   QK_STEP(1, p1)   QK_STEP(2, p2)   QK_STEP(3, p3)
    QK_STEP(4, p4)   QK_STEP(5, p5)   QK_STEP(6, p6)   QK_STEP(7, p7)
    QK_STEP(8, p8)   QK_STEP(9, p9)   QK_STEP(10, p10) QK_STEP(11, p11)
    QK_STEP(12, p12) QK_STEP(13, p13) QK_STEP(14, p14) QK_STEP(15, p15)
    QK_STEP(16, p16) QK_STEP(17, p17) QK_STEP(18, p18) QK_STEP(19, p19)
    QK_STEP(20, p20) QK_STEP(21, p21) QK_STEP(22, p22) QK_STEP(23, p23)
    QK_STEP(24, p24) QK_STEP(25, p25) QK_STEP(26, p26) QK_STEP(27, p27)
    QK_STEP(28, p28) QK_STEP(29, p29) QK_STEP(30, p30) QK_STEP(31, p31)
#undef QK_STEP

    // shuffle-free rowsum reduce: 16 partials per row (4 waves x 4 hq groups)  [r10-verified]
    rpart[rr * 17 + w * 4 + hq] = rs;
    __syncthreads();
    float sum = 0.f;
#pragma unroll
    for (int j = 0; j < 16; j++) sum += rpart[rr * 17 + j];
    float invr = 1.0f / sum;

    // ---- pass B: attns write (normalized f32) + swapped PV on unnormalized named P
    const bf16_t* vb = Vtp + (size_t)bh * DKH * LSEQ;
    float* arow = attn_out + ((size_t)(h * 2 + b) * LSEQ + q0 + rr) * LSEQ;
    f32x4 os0 = {0.f, 0.f, 0.f, 0.f}, os1 = {0.f, 0.f, 0.f, 0.f};
    f32x4 os2 = {0.f, 0.f, 0.f, 0.f}, os3 = {0.f, 0.f, 0.f, 0.f};
#define PV_STEP(J, PA, PB)                                                               \
    {                                                                                    \
        int cb0 = w * 512 + (J) * 32;                                                    \
        float4 w0 = {(float)PA[0] * invr, (float)PA[1] * invr,                           \
                     (float)PA[2] * invr, (float)PA[3] * invr};                          \
        float4 w1 = {(float)PB[0] * invr, (float)PB[1] * invr,                           \
                     (float)PB[2] * invr, (float)PB[3] * invr};                          \
        *reinterpret_cast<float4*>(arow + cb0 + hq * 4) = w0;                            \
        *reinterpret_cast<float4*>(arow + cb0 + 16 + hq * 4) = w1;                       \
        bf16x8 pa;                                                                       \
        pa[0] = PA[0]; pa[1] = PA[1]; pa[2] = PA[2]; pa[3] = PA[3];                      \
        pa[4] = PB[0]; pa[5] = PB[1]; pa[6] = PB[2]; pa[7] = PB[3];                      \
        const bf16_t* vfp = vb + (size_t)rr * LSEQ + cb0 + hq * 8;                       \
        bf16x8 vf0 = *reinterpret_cast<const bf16x8*>(vfp);                              \
        bf16x8 vf1 = *reinterpret_cast<const bf16x8*>(vfp + (size_t)16 * LSEQ);          \
        bf16x8 vf2 = *reinterpret_cast<const bf16x8*>(vfp + (size_t)32 * LSEQ);          \
        bf16x8 vf3 = *reinterpret_cast<const bf16x8*>(vfp + (size_t)48 * LSEQ);          \
        os0 = MFMA16(vf0, pa, os0);                                                      \
        os1 = MFMA16(vf1, pa, os1);                                                      \
        os2 = MFMA16(vf2, pa, os2);                                                      \
        os3 = MFMA16(vf3, pa, os3);                                                      \
    }
    PV_STEP(0, p0, p1)    PV_STEP(1, p2, p3)    PV_STEP(2, p4, p5)    PV_STEP(3, p6, p7)
    PV_STEP(4, p8, p9)    PV_STEP(5, p10, p11)  PV_STEP(6, p12, p13)  PV_STEP(7, p14, p15)
    PV_STEP(8, p16, p17)  PV_STEP(9, p18, p19)  PV_STEP(10, p20, p21) PV_STEP(11, p22, p23)
    PV_STEP(12, p24, p25) PV_STEP(13, p26, p27) PV_STEP(14, p28, p29) PV_STEP(15, p30, p31)
#undef PV_STEP

    // cross-wave O reduce; invr (row q0+rr's inverse, lane-local) folded here  [r10 pattern]
#pragma unroll
    for (int i = 0; i < 4; i++) {
        sO[w * 1040 + rr * 65 + 0 * 16 + hq * 4 + i] = os0[i] * invr;
        sO[w * 1040 + rr * 65 + 1 * 16 + hq * 4 + i] = os1[i] * invr;
        sO[w * 1040 + rr * 65 + 2 * 16 + hq * 4 + i] = os2[i] * invr;
        sO[w * 1040 + rr * 65 + 3 * 16 + hq * 4 + i] = os3[i] * invr;
    }
    __syncthreads();
#pragma unroll
    for (int i = 0; i < 4; i++) {
        int e = i * 256 + t;
        int orow = e >> 6, oc = e & 63;
        float v = sO[orow * 65 + oc] + sO[1040 + orow * 65 + oc] +
                  sO[2080 + orow * 65 + oc] + sO[3120 + orow * 65 + oc];
        Obf[(((size_t)b * LSEQ + q0 + orow) * NHEAD + h) * DKH + oc] = (bf16_t)v;
    }
}

// ----------------------------------------------------------------------- launch
extern "C" void kernel_launch(void* const* d_in, const int* in_sizes, int n_in,
                              void* d_out, int out_size, void* d_ws, size_t ws_size,
                              hipStream_t stream) {
    (void)in_sizes; (void)n_in; (void)out_size; (void)ws_size;
    const float* q = (const float*)d_in[0];
    const int* mask = (const int*)d_in[3];   // int32 (verified r6)
    const float* W_qkv = (const float*)d_in[4];
    const float* b_qkv = (const float*)d_in[5];
    const float* W_proj = (const float*)d_in[6];
    const float* b_proj = (const float*)d_in[7];
    float* out = (float*)d_out;
    float* attn_out = out + (size_t)2 * LSEQ * DMODEL;  // f32 elements

    char* ws = (char*)d_ws;
    bf16_t* wqkv_t = (bf16_t*)(ws);                   // 1.5 MB
    bf16_t* wproj_t = (bf16_t*)(ws + 1572864);        // 0.5 MB
    bf16_t* Qh = (bf16_t*)(ws + 2097152);             // 4 MB
    bf16_t* Kh = (bf16_t*)(ws + 6291456);             // 4 MB
    bf16_t* Vtp = (bf16_t*)(ws + 10485760);           // 4 MB
    bf16_t* Obf = (bf16_t*)(ws + 14680064);           // 4 MB  (total 18 MB)

    k_transpose_cast<<<dim3(48, 16), dim3(32, 8), 0, stream>>>(W_qkv, wqkv_t, 512, 1536);
    k_transpose_cast<<<dim3(16, 16), dim3(32, 8), 0, stream>>>(W_proj, wproj_t, 512, 512);
    k_gemm_nt<0><<<dim3(32, 12), 256, 0, stream>>>(q, wqkv_t, b_qkv, Qh, Kh, Vtp, nullptr, 512);
    k_attn7<<<2048, 256, 0, stream>>>(Qh, Kh, Vtp, mask, attn_out, Obf);
    k_gemm_nt<1><<<dim3(32, 4), 256, 0, stream>>>(Obf, wproj_t, b_proj, nullptr, nullptr, nullptr, out, 512);
}

// Round 14
// 242.755 us; speedup vs baseline: 1.5934x; 1.0155x over previous
//
#include <hip/hip_runtime.h>
#include <hip/hip_bf16.h>
#include <cstdint>
#include <cstddef>

typedef __bf16 bf16_t;
typedef __attribute__((ext_vector_type(4))) __bf16 bf16x4;
typedef __attribute__((ext_vector_type(8))) __bf16 bf16x8;
typedef __attribute__((ext_vector_type(4))) float f32x4;

#define MFMA16(a, b, c) __builtin_amdgcn_mfma_f32_16x16x32_bf16(a, b, c, 0, 0, 0)

constexpr int LSEQ = 2048;
constexpr int DMODEL = 512;
constexpr int NHEAD = 8;
constexpr int DKH = 64;
constexpr float INV_TEMPER = 0.04419417382415922f;  // 1/sqrt(512)

// ------------------------------------------- transpose+cast W [K][N] f32 -> Wt [N][K] bf16
__global__ __launch_bounds__(256) void k_transpose_cast(const float* __restrict__ in,
                                                        bf16_t* __restrict__ out,
                                                        int K, int N) {
    __shared__ float tile[32][33];
    int n0 = blockIdx.x * 32, k0 = blockIdx.y * 32;
    int tx = threadIdx.x, ty = threadIdx.y;
#pragma unroll
    for (int i = 0; i < 4; i++)
        tile[ty + i * 8][tx] = in[(size_t)(k0 + ty + i * 8) * N + n0 + tx];
    __syncthreads();
#pragma unroll
    for (int i = 0; i < 4; i++)
        out[(size_t)(n0 + ty + i * 8) * K + k0 + tx] = (bf16_t)tile[tx][ty + i * 8];
}

// ------------------------------------------- NT GEMM: C[m][n] = A[m][:]·Bt[n][:] + bias
// MODE 0: A f32 (cast in staging); Q -> Qh (scaled), K -> Kh, V -> Vtp (transposed +
//         within-32 k-slot permutation: location 32c+8hq+e holds V[32c+perm(hq,e)]).
// MODE 1: A bf16; f32 out (final projection).
template <int MODE>
__global__ __launch_bounds__(256) void k_gemm_nt(const void* __restrict__ Av,
                                                 const bf16_t* __restrict__ Bt,
                                                 const float* __restrict__ bias,
                                                 bf16_t* __restrict__ outQ,
                                                 bf16_t* __restrict__ outK,
                                                 bf16_t* __restrict__ outV,
                                                 float* __restrict__ outO, int K) {
    __shared__ bf16_t As[128 * 32];
    __shared__ bf16_t Bs[128 * 32];
    int t = threadIdx.x;
    int lane = t & 63, w = t >> 6;
    int wm = w >> 1, wn = w & 1;
    int rr = lane & 15, hq = lane >> 4;
    int m0 = blockIdx.x * 128, n0 = blockIdx.y * 128;
    int srow = t >> 2, sseg = t & 3;
    const float* gaF = (const float*)Av + (size_t)(m0 + srow) * K + sseg * 8;
    const bf16_t* gaB = (const bf16_t*)Av + (size_t)(m0 + srow) * K + sseg * 8;
    const bf16_t* gb = Bt + (size_t)(n0 + srow) * K + sseg * 8;
    f32x4 acc[4][4] = {};
    for (int k0 = 0; k0 < K; k0 += 32) {
        bf16x8 a0, a1;
        if (MODE == 0) {
            float4 l0 = *reinterpret_cast<const float4*>(gaF + k0);
            float4 h0 = *reinterpret_cast<const float4*>(gaF + k0 + 4);
            float4 l1 = *reinterpret_cast<const float4*>(gaF + (size_t)64 * K + k0);
            float4 h1 = *reinterpret_cast<const float4*>(gaF + (size_t)64 * K + k0 + 4);
            a0[0] = (bf16_t)l0.x; a0[1] = (bf16_t)l0.y; a0[2] = (bf16_t)l0.z; a0[3] = (bf16_t)l0.w;
            a0[4] = (bf16_t)h0.x; a0[5] = (bf16_t)h0.y; a0[6] = (bf16_t)h0.z; a0[7] = (bf16_t)h0.w;
            a1[0] = (bf16_t)l1.x; a1[1] = (bf16_t)l1.y; a1[2] = (bf16_t)l1.z; a1[3] = (bf16_t)l1.w;
            a1[4] = (bf16_t)h1.x; a1[5] = (bf16_t)h1.y; a1[6] = (bf16_t)h1.z; a1[7] = (bf16_t)h1.w;
        } else {
            a0 = *reinterpret_cast<const bf16x8*>(gaB + k0);
            a1 = *reinterpret_cast<const bf16x8*>(gaB + (size_t)64 * K + k0);
        }
        uint4 b0 = *reinterpret_cast<const uint4*>(gb + k0);
        uint4 b1 = *reinterpret_cast<const uint4*>(gb + (size_t)64 * K + k0);
        __syncthreads();
        *reinterpret_cast<bf16x8*>(&As[srow * 32 + sseg * 8]) = a0;
        *reinterpret_cast<bf16x8*>(&As[(srow + 64) * 32 + sseg * 8]) = a1;
        *reinterpret_cast<uint4*>(&Bs[srow * 32 + sseg * 8]) = b0;
        *reinterpret_cast<uint4*>(&Bs[(srow + 64) * 32 + sseg * 8]) = b1;
        __syncthreads();
        bf16x8 af[4], bff[4];
#pragma unroll
        for (int i = 0; i < 4; i++) {
            af[i] = *reinterpret_cast<const bf16x8*>(&As[(wm * 64 + i * 16 + rr) * 32 + hq * 8]);
            bff[i] = *reinterpret_cast<const bf16x8*>(&Bs[(wn * 64 + i * 16 + rr) * 32 + hq * 8]);
        }
#pragma unroll
        for (int mi = 0; mi < 4; mi++)
#pragma unroll
            for (int ni = 0; ni < 4; ni++)
                acc[mi][ni] = MFMA16(af[mi], bff[ni], acc[mi][ni]);
    }
    // epilogue (C/D layout: col = lane&15, row = 4*(lane>>4)+reg  [verified in-harness r6/r7/r10])
#pragma unroll
    for (int mi = 0; mi < 4; mi++) {
#pragma unroll
        for (int ni = 0; ni < 4; ni++) {
            int gn = n0 + wn * 64 + ni * 16 + rr;
            float bv = bias[gn];
            int gmb = m0 + wm * 64 + mi * 16 + hq * 4;
            if (MODE == 0) {
                int which = gn >> 9;        // 0=q 1=k 2=v
                int hn = (gn >> 6) & 7;     // head
                int dk = gn & 63;
                if (which == 2) {
                    // V -> Vtp[bh][dk][pos]; within each 32-token group, location
                    // 8hq+e holds token perm(hq,e) = (e<4 ? 4hq+e : 16+4hq+e-4)  [r10-verified]
#pragma unroll
                    for (int rg = 0; rg < 4; rg++) {
                        int gm = gmb + rg;
                        int bb = gm >> 11, ll = gm & 2047;
                        int pos = (ll & ~31) | ((ll & 0xC) << 1) | ((ll & 0x10) >> 2) | (ll & 3);
                        outV[(((size_t)bb * NHEAD + hn) * DKH + dk) * LSEQ + pos] =
                            (bf16_t)(acc[mi][ni][rg] + bv);
                    }
                } else {
                    bf16_t* dst = which == 0 ? outQ : outK;
                    float scale = which == 0 ? INV_TEMPER : 1.0f;
#pragma unroll
                    for (int rg = 0; rg < 4; rg++) {
                        int gm = gmb + rg;
                        int bb = gm >> 11, ll = gm & 2047;
                        float v = (acc[mi][ni][rg] + bv) * scale;
                        dst[(((size_t)bb * NHEAD + hn) * LSEQ + ll) * DKH + dk] = (bf16_t)v;
                    }
                }
            } else {
#pragma unroll
                for (int rg = 0; rg < 4; rg++) {
                    int gm = gmb + rg;
                    outO[(size_t)gm * DMODEL + gn] = acc[mi][ni][rg] + bv;
                }
            }
        }
    }
}

// ------------------------------------------- fused attention v8: 8 waves, 16 P-frags/lane
// Same math/addressing as r13 (r10-verified), but 512 threads/block: each wave covers
// 256 cols -> per-lane P = 16 named bf16x4 (32 VGPRs, half of r13). Halved register
// pressure is the anti-spill fix (r12/r13: allocator kept spilling at 64-VGPR P).
__global__ __launch_bounds__(512, 4) void k_attn8(const bf16_t* __restrict__ Qh,
                                                  const bf16_t* __restrict__ Kh,
                                                  const bf16_t* __restrict__ Vtp,
                                                  const int* __restrict__ mask,
                                                  float* __restrict__ attn_out,
                                                  bf16_t* __restrict__ Obf) {
    __shared__ float sO[8 * 16 * 65];   // 8 wave-slices of O partials, padded stride 65
    __shared__ float rpart[16 * 33];    // [row rr][w*4+hq], 32 partials + pad
    int t = threadIdx.x;
    int lane = t & 63, w = t >> 6;      // w in [0,8)
    int rr = lane & 15, hq = lane >> 4;
    int bid = blockIdx.x;
    int h = bid & 7, b = (bid >> 3) & 1, qt = bid >> 4;
    int q0 = qt * 16;
    int bh = b * NHEAD + h;

    const bf16_t* qp = Qh + ((size_t)bh * LSEQ + q0 + rr) * DKH + hq * 8;
    bf16x8 qf0 = *reinterpret_cast<const bf16x8*>(qp);
    bf16x8 qf1 = *reinterpret_cast<const bf16x8*>(qp + 32);

    const bf16_t* kb = Kh + (size_t)bh * LSEQ * DKH;
    const int* mrow = mask + ((size_t)b * LSEQ + q0 + rr) * LSEQ;

    // 16 named P fragments (bf16x4 = 2 VGPRs each)
    bf16x4 p0, p1, p2, p3, p4, p5, p6, p7, p8, p9, p10, p11, p12, p13, p14, p15;
    float rs = 0.f;

    // ---- pass A: QK^T + mask + exp -> named P (unnormalized) + row sum
    // swapped MFMA [r10-verified]: D[i] = S[q0+rr][cb+4*hq+i]; wave w: cols [w*256,+256)
#define QK_STEP(NT, PD)                                                                  \
    {                                                                                    \
        int cb = w * 256 + (NT) * 16;                                                    \
        const bf16_t* kp = kb + (size_t)(cb + rr) * DKH + hq * 8;                        \
        bf16x8 kf0 = *reinterpret_cast<const bf16x8*>(kp);                               \
        bf16x8 kf1 = *reinterpret_cast<const bf16x8*>(kp + 32);                          \
        f32x4 acc = {0.f, 0.f, 0.f, 0.f};                                                \
        acc = MFMA16(kf0, qf0, acc);                                                     \
        acc = MFMA16(kf1, qf1, acc);                                                     \
        int4 mv = *reinterpret_cast<const int4*>(mrow + cb + hq * 4);                    \
        float e0 = mv.x ? 0.f : __expf(acc[0]);                                          \
        float e1 = mv.y ? 0.f : __expf(acc[1]);                                          \
        float e2 = mv.z ? 0.f : __expf(acc[2]);                                          \
        float e3 = mv.w ? 0.f : __expf(acc[3]);                                          \
        rs += (e0 + e1) + (e2 + e3);                                                     \
        PD[0] = (bf16_t)e0; PD[1] = (bf16_t)e1; PD[2] = (bf16_t)e2; PD[3] = (bf16_t)e3;  \
    }
    QK_STEP(0, p0)   QK_STEP(1, p1)   QK_STEP(2, p2)   QK_STEP(3, p3)
    QK_STEP(4, p4)   QK_STEP(5, p5)   QK_STEP(6, p6)   QK_STEP(7, p7)
    QK_STEP(8, p8)   QK_STEP(9, p9)   QK_STEP(10, p10) QK_STEP(11, p11)
    QK_STEP(12, p12) QK_STEP(13, p13) QK_STEP(14, p14) QK_STEP(15, p15)
#undef QK_STEP

    // shuffle-free rowsum reduce: 32 partials per row (8 waves x 4 hq groups)  [r10 pattern]
    rpart[rr * 33 + w * 4 + hq] = rs;
    __syncthreads();
    float sum = 0.f;
#pragma unroll
    for (int j = 0; j < 32; j++) sum += rpart[rr * 33 + j];
    float invr = 1.0f / sum;

    // ---- pass B: attns write (normalized f32) + swapped PV on unnormalized named P
    const bf16_t* vb = Vtp + (size_t)bh * DKH * LSEQ;
    float* arow = attn_out + ((size_t)(h * 2 + b) * LSEQ + q0 + rr) * LSEQ;
    f32x4 os0 = {0.f, 0.f, 0.f, 0.f}, os1 = {0.f, 0.f, 0.f, 0.f};
    f32x4 os2 = {0.f, 0.f, 0.f, 0.f}, os3 = {0.f, 0.f, 0.f, 0.f};
#define PV_STEP(J, PA, PB)                                                               \
    {                                                                                    \
        int cb0 = w * 256 + (J) * 32;                                                    \
        float4 w0 = {(float)PA[0] * invr, (float)PA[1] * invr,                           \
                     (float)PA[2] * invr, (float)PA[3] * invr};                          \
        float4 w1 = {(float)PB[0] * invr, (float)PB[1] * invr,                           \
                     (float)PB[2] * invr, (float)PB[3] * invr};                          \
        *reinterpret_cast<float4*>(arow + cb0 + hq * 4) = w0;                            \
        *reinterpret_cast<float4*>(arow + cb0 + 16 + hq * 4) = w1;                       \
        bf16x8 pa;                                                                       \
        pa[0] = PA[0]; pa[1] = PA[1]; pa[2] = PA[2]; pa[3] = PA[3];                      \
        pa[4] = PB[0]; pa[5] = PB[1]; pa[6] = PB[2]; pa[7] = PB[3];                      \
        const bf16_t* vfp = vb + (size_t)rr * LSEQ + cb0 + hq * 8;                       \
        bf16x8 vf0 = *reinterpret_cast<const bf16x8*>(vfp);                              \
        bf16x8 vf1 = *reinterpret_cast<const bf16x8*>(vfp + (size_t)16 * LSEQ);          \
        bf16x8 vf2 = *reinterpret_cast<const bf16x8*>(vfp + (size_t)32 * LSEQ);          \
        bf16x8 vf3 = *reinterpret_cast<const bf16x8*>(vfp + (size_t)48 * LSEQ);          \
        os0 = MFMA16(vf0, pa, os0);                                                      \
        os1 = MFMA16(vf1, pa, os1);                                                      \
        os2 = MFMA16(vf2, pa, os2);                                                      \
        os3 = MFMA16(vf3, pa, os3);                                                      \
    }
    PV_STEP(0, p0, p1)   PV_STEP(1, p2, p3)   PV_STEP(2, p4, p5)   PV_STEP(3, p6, p7)
    PV_STEP(4, p8, p9)   PV_STEP(5, p10, p11) PV_STEP(6, p12, p13) PV_STEP(7, p14, p15)
#undef PV_STEP

    // cross-wave O reduce; invr (row q0+rr's inverse, lane-local) folded here  [r10 pattern]
#pragma unroll
    for (int i = 0; i < 4; i++) {
        sO[w * 1040 + rr * 65 + 0 * 16 + hq * 4 + i] = os0[i] * invr;
        sO[w * 1040 + rr * 65 + 1 * 16 + hq * 4 + i] = os1[i] * invr;
        sO[w * 1040 + rr * 65 + 2 * 16 + hq * 4 + i] = os2[i] * invr;
        sO[w * 1040 + rr * 65 + 3 * 16 + hq * 4 + i] = os3[i] * invr;
    }
    __syncthreads();
#pragma unroll
    for (int i = 0; i < 2; i++) {
        int e = i * 512 + t;
        int orow = e >> 6, oc = e & 63;
        float v = 0.f;
#pragma unroll
        for (int ww = 0; ww < 8; ww++) v += sO[ww * 1040 + orow * 65 + oc];
        Obf[(((size_t)b * LSEQ + q0 + orow) * NHEAD + h) * DKH + oc] = (bf16_t)v;
    }
}

// ----------------------------------------------------------------------- launch
extern "C" void kernel_launch(void* const* d_in, const int* in_sizes, int n_in,
                              void* d_out, int out_size, void* d_ws, size_t ws_size,
                              hipStream_t stream) {
    (void)in_sizes; (void)n_in; (void)out_size; (void)ws_size;
    const float* q = (const float*)d_in[0];
    const int* mask = (const int*)d_in[3];   // int32 (verified r6)
    const float* W_qkv = (const float*)d_in[4];
    const float* b_qkv = (const float*)d_in[5];
    const float* W_proj = (const float*)d_in[6];
    const float* b_proj = (const float*)d_in[7];
    float* out = (float*)d_out;
    float* attn_out = out + (size_t)2 * LSEQ * DMODEL;  // f32 elements

    char* ws = (char*)d_ws;
    bf16_t* wqkv_t = (bf16_t*)(ws);                   // 1.5 MB
    bf16_t* wproj_t = (bf16_t*)(ws + 1572864);        // 0.5 MB
    bf16_t* Qh = (bf16_t*)(ws + 2097152);             // 4 MB
    bf16_t* Kh = (bf16_t*)(ws + 6291456);             // 4 MB
    bf16_t* Vtp = (bf16_t*)(ws + 10485760);           // 4 MB
    bf16_t* Obf = (bf16_t*)(ws + 14680064);           // 4 MB  (total 18 MB)

    k_transpose_cast<<<dim3(48, 16), dim3(32, 8), 0, stream>>>(W_qkv, wqkv_t, 512, 1536);
    k_transpose_cast<<<dim3(16, 16), dim3(32, 8), 0, stream>>>(W_proj, wproj_t, 512, 512);
    k_gemm_nt<0><<<dim3(32, 12), 256, 0, stream>>>(q, wqkv_t, b_qkv, Qh, Kh, Vtp, nullptr, 512);
    k_attn8<<<2048, 512, 0, stream>>>(Qh, Kh, Vtp, mask, attn_out, Obf);
    k_gemm_nt<1><<<dim3(32, 4), 256, 0, stream>>>(Obf, wproj_t, b_proj, nullptr, nullptr, nullptr, out, 512);
}

// Round 15
// 239.686 us; speedup vs baseline: 1.6138x; 1.0128x over previous
//
#include <hip/hip_runtime.h>
#include <hip/hip_bf16.h>
#include <cstdint>
#include <cstddef>

typedef __bf16 bf16_t;
typedef __attribute__((ext_vector_type(4))) __bf16 bf16x4;
typedef __attribute__((ext_vector_type(8))) __bf16 bf16x8;
typedef __attribute__((ext_vector_type(4))) float f32x4;

#define MFMA16(a, b, c) __builtin_amdgcn_mfma_f32_16x16x32_bf16(a, b, c, 0, 0, 0)

constexpr int LSEQ = 2048;
constexpr int DMODEL = 512;
constexpr int NHEAD = 8;
constexpr int DKH = 64;
constexpr float INV_TEMPER = 0.04419417382415922f;  // 1/sqrt(512)

// ------------------------------------------- transpose+cast W [K][N] f32 -> Wt [N][K] bf16
__global__ __launch_bounds__(256) void k_transpose_cast(const float* __restrict__ in,
                                                        bf16_t* __restrict__ out,
                                                        int K, int N) {
    __shared__ float tile[32][33];
    int n0 = blockIdx.x * 32, k0 = blockIdx.y * 32;
    int tx = threadIdx.x, ty = threadIdx.y;
#pragma unroll
    for (int i = 0; i < 4; i++)
        tile[ty + i * 8][tx] = in[(size_t)(k0 + ty + i * 8) * N + n0 + tx];
    __syncthreads();
#pragma unroll
    for (int i = 0; i < 4; i++)
        out[(size_t)(n0 + ty + i * 8) * K + k0 + tx] = (bf16_t)tile[tx][ty + i * 8];
}

// ------------------------------------------- NT GEMM: C[m][n] = A[m][:]·Bt[n][:] + bias
// MODE 0: A f32 (cast in staging); Q -> Qh (scaled), K -> Kh, V -> Vtp (transposed +
//         within-32 k-slot permutation: location 32c+8hq+e holds V[32c+perm(hq,e)]).
// MODE 1: A bf16; f32 out (final projection).
template <int MODE>
__global__ __launch_bounds__(256) void k_gemm_nt(const void* __restrict__ Av,
                                                 const bf16_t* __restrict__ Bt,
                                                 const float* __restrict__ bias,
                                                 bf16_t* __restrict__ outQ,
                                                 bf16_t* __restrict__ outK,
                                                 bf16_t* __restrict__ outV,
                                                 float* __restrict__ outO, int K) {
    __shared__ bf16_t As[128 * 32];
    __shared__ bf16_t Bs[128 * 32];
    int t = threadIdx.x;
    int lane = t & 63, w = t >> 6;
    int wm = w >> 1, wn = w & 1;
    int rr = lane & 15, hq = lane >> 4;
    int m0 = blockIdx.x * 128, n0 = blockIdx.y * 128;
    int srow = t >> 2, sseg = t & 3;
    const float* gaF = (const float*)Av + (size_t)(m0 + srow) * K + sseg * 8;
    const bf16_t* gaB = (const bf16_t*)Av + (size_t)(m0 + srow) * K + sseg * 8;
    const bf16_t* gb = Bt + (size_t)(n0 + srow) * K + sseg * 8;
    f32x4 acc[4][4] = {};
    for (int k0 = 0; k0 < K; k0 += 32) {
        bf16x8 a0, a1;
        if (MODE == 0) {
            float4 l0 = *reinterpret_cast<const float4*>(gaF + k0);
            float4 h0 = *reinterpret_cast<const float4*>(gaF + k0 + 4);
            float4 l1 = *reinterpret_cast<const float4*>(gaF + (size_t)64 * K + k0);
            float4 h1 = *reinterpret_cast<const float4*>(gaF + (size_t)64 * K + k0 + 4);
            a0[0] = (bf16_t)l0.x; a0[1] = (bf16_t)l0.y; a0[2] = (bf16_t)l0.z; a0[3] = (bf16_t)l0.w;
            a0[4] = (bf16_t)h0.x; a0[5] = (bf16_t)h0.y; a0[6] = (bf16_t)h0.z; a0[7] = (bf16_t)h0.w;
            a1[0] = (bf16_t)l1.x; a1[1] = (bf16_t)l1.y; a1[2] = (bf16_t)l1.z; a1[3] = (bf16_t)l1.w;
            a1[4] = (bf16_t)h1.x; a1[5] = (bf16_t)h1.y; a1[6] = (bf16_t)h1.z; a1[7] = (bf16_t)h1.w;
        } else {
            a0 = *reinterpret_cast<const bf16x8*>(gaB + k0);
            a1 = *reinterpret_cast<const bf16x8*>(gaB + (size_t)64 * K + k0);
        }
        uint4 b0 = *reinterpret_cast<const uint4*>(gb + k0);
        uint4 b1 = *reinterpret_cast<const uint4*>(gb + (size_t)64 * K + k0);
        __syncthreads();
        *reinterpret_cast<bf16x8*>(&As[srow * 32 + sseg * 8]) = a0;
        *reinterpret_cast<bf16x8*>(&As[(srow + 64) * 32 + sseg * 8]) = a1;
        *reinterpret_cast<uint4*>(&Bs[srow * 32 + sseg * 8]) = b0;
        *reinterpret_cast<uint4*>(&Bs[(srow + 64) * 32 + sseg * 8]) = b1;
        __syncthreads();
        bf16x8 af[4], bff[4];
#pragma unroll
        for (int i = 0; i < 4; i++) {
            af[i] = *reinterpret_cast<const bf16x8*>(&As[(wm * 64 + i * 16 + rr) * 32 + hq * 8]);
            bff[i] = *reinterpret_cast<const bf16x8*>(&Bs[(wn * 64 + i * 16 + rr) * 32 + hq * 8]);
        }
#pragma unroll
        for (int mi = 0; mi < 4; mi++)
#pragma unroll
            for (int ni = 0; ni < 4; ni++)
                acc[mi][ni] = MFMA16(af[mi], bff[ni], acc[mi][ni]);
    }
    // epilogue (C/D layout: col = lane&15, row = 4*(lane>>4)+reg  [verified in-harness r6/r7/r10])
#pragma unroll
    for (int mi = 0; mi < 4; mi++) {
#pragma unroll
        for (int ni = 0; ni < 4; ni++) {
            int gn = n0 + wn * 64 + ni * 16 + rr;
            float bv = bias[gn];
            int gmb = m0 + wm * 64 + mi * 16 + hq * 4;
            if (MODE == 0) {
                int which = gn >> 9;        // 0=q 1=k 2=v
                int hn = (gn >> 6) & 7;     // head
                int dk = gn & 63;
                if (which == 2) {
                    // V -> Vtp[bh][dk][pos]; within each 32-token group, location
                    // 8hq+e holds token perm(hq,e) = (e<4 ? 4hq+e : 16+4hq+e-4)  [r10-verified]
#pragma unroll
                    for (int rg = 0; rg < 4; rg++) {
                        int gm = gmb + rg;
                        int bb = gm >> 11, ll = gm & 2047;
                        int pos = (ll & ~31) | ((ll & 0xC) << 1) | ((ll & 0x10) >> 2) | (ll & 3);
                        outV[(((size_t)bb * NHEAD + hn) * DKH + dk) * LSEQ + pos] =
                            (bf16_t)(acc[mi][ni][rg] + bv);
                    }
                } else {
                    bf16_t* dst = which == 0 ? outQ : outK;
                    float scale = which == 0 ? INV_TEMPER : 1.0f;
#pragma unroll
                    for (int rg = 0; rg < 4; rg++) {
                        int gm = gmb + rg;
                        int bb = gm >> 11, ll = gm & 2047;
                        float v = (acc[mi][ni][rg] + bv) * scale;
                        dst[(((size_t)bb * NHEAD + hn) * LSEQ + ll) * DKH + dk] = (bf16_t)v;
                    }
                }
            } else {
#pragma unroll
                for (int rg = 0; rg < 4; rg++) {
                    int gm = gmb + rg;
                    outO[(size_t)gm * DMODEL + gn] = acc[mi][ni][rg] + bv;
                }
            }
        }
    }
}

// ------------------------------------------- fused attention v9: v8 + VMEM sched fences
// r14 structure (8 waves, 16 named P-frags/lane) + __builtin_amdgcn_sched_barrier(0x38F)
// after every step: blocks VMEM (0x10|0x20|0x40) from crossing step boundaries so the
// scheduler can't hoist all 16 K-load pairs (the r12-r14 spill cause: ~128 VGPRs of
// in-flight loads forced RA to shed P to scratch). ALU/VALU/SALU/MFMA/DS may cross.
#define SCHED_FENCE() __builtin_amdgcn_sched_barrier(0x38F)

__global__ __launch_bounds__(512, 4) void k_attn9(const bf16_t* __restrict__ Qh,
                                                  const bf16_t* __restrict__ Kh,
                                                  const bf16_t* __restrict__ Vtp,
                                                  const int* __restrict__ mask,
                                                  float* __restrict__ attn_out,
                                                  bf16_t* __restrict__ Obf) {
    __shared__ float sO[8 * 16 * 65];   // 8 wave-slices of O partials, padded stride 65
    __shared__ float rpart[16 * 33];    // [row rr][w*4+hq], 32 partials + pad
    int t = threadIdx.x;
    int lane = t & 63, w = t >> 6;      // w in [0,8)
    int rr = lane & 15, hq = lane >> 4;
    int bid = blockIdx.x;
    int h = bid & 7, b = (bid >> 3) & 1, qt = bid >> 4;
    int q0 = qt * 16;
    int bh = b * NHEAD + h;

    const bf16_t* qp = Qh + ((size_t)bh * LSEQ + q0 + rr) * DKH + hq * 8;
    bf16x8 qf0 = *reinterpret_cast<const bf16x8*>(qp);
    bf16x8 qf1 = *reinterpret_cast<const bf16x8*>(qp + 32);

    const bf16_t* kb = Kh + (size_t)bh * LSEQ * DKH;
    const int* mrow = mask + ((size_t)b * LSEQ + q0 + rr) * LSEQ;

    // 16 named P fragments (bf16x4 = 2 VGPRs each)
    bf16x4 p0, p1, p2, p3, p4, p5, p6, p7, p8, p9, p10, p11, p12, p13, p14, p15;
    float rs = 0.f;

    // ---- pass A: QK^T + mask + exp -> named P (unnormalized) + row sum
    // swapped MFMA [r10-verified]: D[i] = S[q0+rr][cb+4*hq+i]; wave w: cols [w*256,+256)
#define QK_STEP(NT, PD)                                                                  \
    {                                                                                    \
        int cb = w * 256 + (NT) * 16;                                                    \
        const bf16_t* kp = kb + (size_t)(cb + rr) * DKH + hq * 8;                        \
        bf16x8 kf0 = *reinterpret_cast<const bf16x8*>(kp);                               \
        bf16x8 kf1 = *reinterpret_cast<const bf16x8*>(kp + 32);                          \
        f32x4 acc = {0.f, 0.f, 0.f, 0.f};                                                \
        acc = MFMA16(kf0, qf0, acc);                                                     \
        acc = MFMA16(kf1, qf1, acc);                                                     \
        int4 mv = *reinterpret_cast<const int4*>(mrow + cb + hq * 4);                    \
        float e0 = mv.x ? 0.f : __expf(acc[0]);                                          \
        float e1 = mv.y ? 0.f : __expf(acc[1]);                                          \
        float e2 = mv.z ? 0.f : __expf(acc[2]);                                          \
        float e3 = mv.w ? 0.f : __expf(acc[3]);                                          \
        rs += (e0 + e1) + (e2 + e3);                                                     \
        PD[0] = (bf16_t)e0; PD[1] = (bf16_t)e1; PD[2] = (bf16_t)e2; PD[3] = (bf16_t)e3;  \
        SCHED_FENCE();                                                                   \
    }
    QK_STEP(0, p0)   QK_STEP(1, p1)   QK_STEP(2, p2)   QK_STEP(3, p3)
    QK_STEP(4, p4)   QK_STEP(5, p5)   QK_STEP(6, p6)   QK_STEP(7, p7)
    QK_STEP(8, p8)   QK_STEP(9, p9)   QK_STEP(10, p10) QK_STEP(11, p11)
    QK_STEP(12, p12) QK_STEP(13, p13) QK_STEP(14, p14) QK_STEP(15, p15)
#undef QK_STEP

    // shuffle-free rowsum reduce: 32 partials per row (8 waves x 4 hq groups)  [r10 pattern]
    rpart[rr * 33 + w * 4 + hq] = rs;
    __syncthreads();
    float sum = 0.f;
#pragma unroll
    for (int j = 0; j < 32; j++) sum += rpart[rr * 33 + j];
    float invr = 1.0f / sum;

    // ---- pass B: attns write (normalized f32) + swapped PV on unnormalized named P
    const bf16_t* vb = Vtp + (size_t)bh * DKH * LSEQ;
    float* arow = attn_out + ((size_t)(h * 2 + b) * LSEQ + q0 + rr) * LSEQ;
    f32x4 os0 = {0.f, 0.f, 0.f, 0.f}, os1 = {0.f, 0.f, 0.f, 0.f};
    f32x4 os2 = {0.f, 0.f, 0.f, 0.f}, os3 = {0.f, 0.f, 0.f, 0.f};
#define PV_STEP(J, PA, PB)                                                               \
    {                                                                                    \
        int cb0 = w * 256 + (J) * 32;                                                    \
        float4 w0 = {(float)PA[0] * invr, (float)PA[1] * invr,                           \
                     (float)PA[2] * invr, (float)PA[3] * invr};                          \
        float4 w1 = {(float)PB[0] * invr, (float)PB[1] * invr,                           \
                     (float)PB[2] * invr, (float)PB[3] * invr};                          \
        *reinterpret_cast<float4*>(arow + cb0 + hq * 4) = w0;                            \
        *reinterpret_cast<float4*>(arow + cb0 + 16 + hq * 4) = w1;                       \
        bf16x8 pa;                                                                       \
        pa[0] = PA[0]; pa[1] = PA[1]; pa[2] = PA[2]; pa[3] = PA[3];                      \
        pa[4] = PB[0]; pa[5] = PB[1]; pa[6] = PB[2]; pa[7] = PB[3];                      \
        const bf16_t* vfp = vb + (size_t)rr * LSEQ + cb0 + hq * 8;                       \
        bf16x8 vf0 = *reinterpret_cast<const bf16x8*>(vfp);                              \
        bf16x8 vf1 = *reinterpret_cast<const bf16x8*>(vfp + (size_t)16 * LSEQ);          \
        bf16x8 vf2 = *reinterpret_cast<const bf16x8*>(vfp + (size_t)32 * LSEQ);          \
        bf16x8 vf3 = *reinterpret_cast<const bf16x8*>(vfp + (size_t)48 * LSEQ);          \
        os0 = MFMA16(vf0, pa, os0);                                                      \
        os1 = MFMA16(vf1, pa, os1);                                                      \
        os2 = MFMA16(vf2, pa, os2);                                                      \
        os3 = MFMA16(vf3, pa, os3);                                                      \
        SCHED_FENCE();                                                                   \
    }
    PV_STEP(0, p0, p1)   PV_STEP(1, p2, p3)   PV_STEP(2, p4, p5)   PV_STEP(3, p6, p7)
    PV_STEP(4, p8, p9)   PV_STEP(5, p10, p11) PV_STEP(6, p12, p13) PV_STEP(7, p14, p15)
#undef PV_STEP

    // cross-wave O reduce; invr (row q0+rr's inverse, lane-local) folded here  [r10 pattern]
#pragma unroll
    for (int i = 0; i < 4; i++) {
        sO[w * 1040 + rr * 65 + 0 * 16 + hq * 4 + i] = os0[i] * invr;
        sO[w * 1040 + rr * 65 + 1 * 16 + hq * 4 + i] = os1[i] * invr;
        sO[w * 1040 + rr * 65 + 2 * 16 + hq * 4 + i] = os2[i] * invr;
        sO[w * 1040 + rr * 65 + 3 * 16 + hq * 4 + i] = os3[i] * invr;
    }
    __syncthreads();
#pragma unroll
    for (int i = 0; i < 2; i++) {
        int e = i * 512 + t;
        int orow = e >> 6, oc = e & 63;
        float v = 0.f;
#pragma unroll
        for (int ww = 0; ww < 8; ww++) v += sO[ww * 1040 + orow * 65 + oc];
        Obf[(((size_t)b * LSEQ + q0 + orow) * NHEAD + h) * DKH + oc] = (bf16_t)v;
    }
}

// ----------------------------------------------------------------------- launch
extern "C" void kernel_launch(void* const* d_in, const int* in_sizes, int n_in,
                              void* d_out, int out_size, void* d_ws, size_t ws_size,
                              hipStream_t stream) {
    (void)in_sizes; (void)n_in; (void)out_size; (void)ws_size;
    const float* q = (const float*)d_in[0];
    const int* mask = (const int*)d_in[3];   // int32 (verified r6)
    const float* W_qkv = (const float*)d_in[4];
    const float* b_qkv = (const float*)d_in[5];
    const float* W_proj = (const float*)d_in[6];
    const float* b_proj = (const float*)d_in[7];
    float* out = (float*)d_out;
    float* attn_out = out + (size_t)2 * LSEQ * DMODEL;  // f32 elements

    char* ws = (char*)d_ws;
    bf16_t* wqkv_t = (bf16_t*)(ws);                   // 1.5 MB
    bf16_t* wproj_t = (bf16_t*)(ws + 1572864);        // 0.5 MB
    bf16_t* Qh = (bf16_t*)(ws + 2097152);             // 4 MB
    bf16_t* Kh = (bf16_t*)(ws + 6291456);             // 4 MB
    bf16_t* Vtp = (bf16_t*)(ws + 10485760);           // 4 MB
    bf16_t* Obf = (bf16_t*)(ws + 14680064);           // 4 MB  (total 18 MB)

    k_transpose_cast<<<dim3(48, 16), dim3(32, 8), 0, stream>>>(W_qkv, wqkv_t, 512, 1536);
    k_transpose_cast<<<dim3(16, 16), dim3(32, 8), 0, stream>>>(W_proj, wproj_t, 512, 512);
    k_gemm_nt<0><<<dim3(32, 12), 256, 0, stream>>>(q, wqkv_t, b_qkv, Qh, Kh, Vtp, nullptr, 512);
    k_attn9<<<2048, 512, 0, stream>>>(Qh, Kh, Vtp, mask, attn_out, Obf);
    k_gemm_nt<1><<<dim3(32, 4), 256, 0, stream>>>(Obf, wproj_t, b_proj, nullptr, nullptr, nullptr, out, 512);
}